// Round 3
// baseline (660.677 us; speedup 1.0000x reference)
//
#include <hip/hip_runtime.h>

#define BB 32
#define CC 3072
#define HWD 784     // 28*28
#define L1 9
#define NCLS 200
#define CSPLIT 16
#define CCHUNK 192  // CC / CSPLIT
#define WROW 12     // padded wT row (floats)

// d_out layout (floats):
#define AF_OFF     0
#define MAPS_OFF   884736
#define SCORES_OFF 1110528
#define DIST_OFF   1161728

// ws layout (floats):
#define P_OFF   0
#define P_CNT   (BB*CSPLIT*10*HWD)      // 4,014,080  partial[(b*16+cs)*10+row][pix]
#define WT_OFF  (P_OFF + P_CNT)
#define WT_CNT  (CC*WROW)
#define ASQ_OFF (WT_OFF + WT_CNT)
#define ASQ_CNT (12*WROW)
#define AFT_OFF (ASQ_OFF + ASQ_CNT)

// ---------------- kW: transpose w_land -> wT[c][12], per-chunk asq partials ----
__global__ __launch_bounds__(256) void kW(const float* __restrict__ w_land,
                                          float* __restrict__ wT,
                                          float* __restrict__ asqp) {
    __shared__ float red[4][L1];
    const int tid = threadIdx.x;
    const int c = blockIdx.x * 256 + tid;
    float w[L1], s[L1];
    #pragma unroll
    for (int l = 0; l < L1; ++l) w[l] = w_land[l * CC + c];
    #pragma unroll
    for (int l = 0; l < L1; ++l) { wT[c * WROW + l] = w[l]; s[l] = w[l] * w[l]; }
    wT[c * WROW + 9] = 0.f; wT[c * WROW + 10] = 0.f; wT[c * WROW + 11] = 0.f;
    #pragma unroll
    for (int l = 0; l < L1; ++l) {
        float v = s[l];
        for (int off = 32; off; off >>= 1) v += __shfl_xor(v, off);
        s[l] = v;
    }
    const int lane = tid & 63, wv = tid >> 6;
    if (lane == 0) {
        #pragma unroll
        for (int l = 0; l < L1; ++l) red[wv][l] = s[l];
    }
    __syncthreads();
    if (tid == 0) {
        #pragma unroll
        for (int l = 0; l < L1; ++l)
            asqp[blockIdx.x * WROW + l] = red[0][l] + red[1][l] + red[2][l] + red[3][l];
    }
}

// ---------------- kA: partial ab[9]+bsq. grid (32 b, 16 cs), thread = 4 pixels ----
__global__ __launch_bounds__(256) void kA(const float* __restrict__ feat,
                                          const float* __restrict__ wT,
                                          float* __restrict__ partial) {
    const int tid = threadIdx.x;
    if (tid >= HWD / 4) return;          // 196 active threads, no barriers
    const int b = blockIdx.x, cs = blockIdx.y;
    const int p4 = tid * 4;
    const float* fp = feat + ((size_t)b * CC + (size_t)cs * CCHUNK) * HWD + p4;
    const float* wp = wT + (size_t)cs * CCHUNK * WROW;   // block-uniform -> s_load

    float abx[L1], aby[L1], abz[L1], abw[L1];
    #pragma unroll
    for (int l = 0; l < L1; ++l) { abx[l] = 0.f; aby[l] = 0.f; abz[l] = 0.f; abw[l] = 0.f; }
    float bx = 0.f, by = 0.f, bz = 0.f, bw = 0.f;

    #pragma unroll 4
    for (int c = 0; c < CCHUNK; ++c) {
        const float4 f = *(const float4*)&fp[(size_t)c * HWD];
        bx += f.x * f.x; by += f.y * f.y; bz += f.z * f.z; bw += f.w * f.w;
        #pragma unroll
        for (int l = 0; l < L1; ++l) {
            const float w = wp[c * WROW + l];
            abx[l] += f.x * w; aby[l] += f.y * w; abz[l] += f.z * w; abw[l] += f.w * w;
        }
    }
    float* pout = partial + (size_t)(b * CSPLIT + cs) * 10 * HWD + p4;
    #pragma unroll
    for (int l = 0; l < L1; ++l) {
        float4 o; o.x = abx[l]; o.y = aby[l]; o.z = abz[l]; o.w = abw[l];
        *(float4*)&pout[(size_t)l * HWD] = o;
    }
    float4 o; o.x = bx; o.y = by; o.z = bz; o.w = bw;
    *(float4*)&pout[(size_t)9 * HWD] = o;
}

// ---------------- kB: reduce partials, softmax -> maps, dist ----------------
__global__ __launch_bounds__(256) void kB(const float* __restrict__ partial,
                                          const float* __restrict__ asqp,
                                          float* __restrict__ maps_out,
                                          float* __restrict__ dist_out) {
    const int b = blockIdx.x >> 2, pb = blockIdx.x & 3;
    const int pix = pb * 256 + threadIdx.x;
    if (pix >= HWD) return;

    float asq[L1];
    #pragma unroll
    for (int l = 0; l < L1; ++l) {
        float s = 0.f;
        #pragma unroll
        for (int bc = 0; bc < 12; ++bc) s += asqp[bc * WROW + l];  // uniform
        asq[l] = s;
    }

    float ab[L1], bsq = 0.f;
    #pragma unroll
    for (int l = 0; l < L1; ++l) ab[l] = 0.f;
    const float* pp = partial + (size_t)b * CSPLIT * 10 * HWD + pix;
    #pragma unroll 4
    for (int cs = 0; cs < CSPLIT; ++cs) {
        const float* q = pp + (size_t)cs * 10 * HWD;
        #pragma unroll
        for (int l = 0; l < L1; ++l) ab[l] += q[(size_t)l * HWD];
        bsq += q[(size_t)9 * HWD];
    }

    float d[L1], mn = 1e30f;
    #pragma unroll
    for (int l = 0; l < L1; ++l) {
        d[l] = bsq - 2.f * ab[l] + asq[l];
        mn = fminf(mn, d[l]);
    }
    float e[L1], sum = 0.f;
    #pragma unroll
    for (int l = 0; l < L1; ++l) {
        e[l] = __expf(mn - d[l]);
        sum += e[l];
    }
    const float inv = 1.f / sum;
    #pragma unroll
    for (int l = 0; l < L1; ++l) {
        const size_t o = ((size_t)b * L1 + l) * HWD + pix;
        maps_out[o] = e[l] * inv;
        dist_out[o] = d[l];
    }
}

// ---------------- kC: all_features via LDS transpose, NO shuffle reduce ---------
// grid (24, 32): x = 128-channel tile, y = b. 256 threads.
// LDS tile [128][113] f32; lane = channel (owns 2: lane, lane+64); waves split
// pixels 4-ways (28 per wave per 112-px chunk). maps reads are wave-uniform ->
// s_load (wave id forced to SGPR via readfirstlane).
#define KCH 128
#define KCK 112
#define KST 113
__global__ __launch_bounds__(256) void kC(const float* __restrict__ feat,
                                          const float* __restrict__ maps,
                                          const float* __restrict__ modulation,
                                          float* __restrict__ af_out,
                                          float* __restrict__ afT) {
    __shared__ float fs[KCH * KST];   // 57,856 B
    const int tid = threadIdx.x;
    const int b = blockIdx.y;
    const int c0 = blockIdx.x * KCH;
    const int w = __builtin_amdgcn_readfirstlane(tid >> 6);  // SGPR wave id
    const int lane = tid & 63;
    const float* fb = feat + ((size_t)b * CC + c0) * HWD;
    const float* mbase = maps + (size_t)b * L1 * HWD;

    float acc0[L1], acc1[L1];
    #pragma unroll
    for (int l = 0; l < L1; ++l) { acc0[l] = 0.f; acc1[l] = 0.f; }

    for (int k = 0; k < HWD / KCK; ++k) {   // 7 chunks
        for (int i = tid; i < KCH * KCK / 2; i += 256) {
            const int row = i / (KCK / 2);
            const int p2 = i - row * (KCK / 2);
            const float2 v = *(const float2*)&fb[(size_t)row * HWD + k * KCK + p2 * 2];
            fs[row * KST + p2 * 2]     = v.x;
            fs[row * KST + p2 * 2 + 1] = v.y;
        }
        __syncthreads();
        const float* mp = mbase + k * KCK + w * (KCK / 4);   // uniform -> s_load
        const float* r0 = &fs[lane * KST + w * (KCK / 4)];
        const float* r1 = &fs[(lane + 64) * KST + w * (KCK / 4)];
        #pragma unroll 4
        for (int p = 0; p < KCK / 4; ++p) {
            float m[L1];
            #pragma unroll
            for (int l = 0; l < L1; ++l) m[l] = mp[(size_t)l * HWD + p];
            const float f0 = r0[p], f1 = r1[p];
            #pragma unroll
            for (int l = 0; l < L1; ++l) { acc0[l] += f0 * m[l]; acc1[l] += f1 * m[l]; }
        }
        __syncthreads();
    }

    // cross-wave reduce through LDS (reuse fs): red[w][j*576 + l*64 + lane]
    #pragma unroll
    for (int l = 0; l < L1; ++l) {
        fs[w * 1152 + l * 64 + lane]       = acc0[l];
        fs[w * 1152 + 576 + l * 64 + lane] = acc1[l];
    }
    __syncthreads();
    for (int idx = tid; idx < 1152; idx += 256) {
        const int j = idx / 576;
        const int rem = idx - j * 576;
        const int l = rem >> 6;
        const int cl = rem & 63;
        const int c = c0 + j * 64 + cl;
        const float s = (fs[idx] + fs[1152 + idx] + fs[2304 + idx] + fs[3456 + idx])
                        * (1.f / (float)HWD);
        af_out[((size_t)b * CC + c) * L1 + l] = s;
        if (l < 8)
            afT[((size_t)b * 8 + l) * CC + c] = s * modulation[c * L1 + l];
    }
}

// ---------------- kD: scores = afT x w_cls^T. wave per (b, 2 classes) -----------
__global__ __launch_bounds__(256) void kD(const float* __restrict__ afT,
                                          const float* __restrict__ w_cls,
                                          float* __restrict__ scores) {
    const int wid = blockIdx.x * 4 + (threadIdx.x >> 6);
    const int lane = threadIdx.x & 63;
    const int b = wid / (NCLS / 2), kp = wid - b * (NCLS / 2);
    const int k0 = kp * 2;
    const float* at = afT + (size_t)b * 8 * CC;
    const float* w0 = w_cls + (size_t)k0 * CC;
    const float* w1 = w0 + CC;

    float acc[2][8];
    #pragma unroll
    for (int kk = 0; kk < 2; ++kk)
        #pragma unroll
        for (int l = 0; l < 8; ++l) acc[kk][l] = 0.f;

    #pragma unroll 2
    for (int it = 0; it < CC / 256; ++it) {
        const int c4 = (lane + it * 64) * 4;
        const float4 wa = *(const float4*)&w0[c4];
        const float4 wb = *(const float4*)&w1[c4];
        #pragma unroll
        for (int l = 0; l < 8; ++l) {
            const float4 a = *(const float4*)&at[(size_t)l * CC + c4];
            acc[0][l] += wa.x * a.x + wa.y * a.y + wa.z * a.z + wa.w * a.w;
            acc[1][l] += wb.x * a.x + wb.y * a.y + wb.z * a.z + wb.w * a.w;
        }
    }
    #pragma unroll
    for (int kk = 0; kk < 2; ++kk)
        #pragma unroll
        for (int l = 0; l < 8; ++l) {
            float v = acc[kk][l];
            for (int off = 32; off; off >>= 1) v += __shfl_xor(v, off);
            acc[kk][l] = v;
        }
    if (lane == 0) {
        #pragma unroll
        for (int kk = 0; kk < 2; ++kk)
            #pragma unroll
            for (int l = 0; l < 8; ++l)
                scores[((size_t)b * NCLS + k0 + kk) * 8 + l] = acc[kk][l];
    }
}

extern "C" void kernel_launch(void* const* d_in, const int* in_sizes, int n_in,
                              void* d_out, int out_size, void* d_ws, size_t ws_size,
                              hipStream_t stream) {
    const float* feat       = (const float*)d_in[0];
    const float* w_land     = (const float*)d_in[1];
    const float* modulation = (const float*)d_in[2];
    const float* w_cls      = (const float*)d_in[3];

    float* out    = (float*)d_out;
    float* af     = out + AF_OFF;
    float* maps   = out + MAPS_OFF;
    float* scores = out + SCORES_OFF;
    float* dist   = out + DIST_OFF;

    float* ws      = (float*)d_ws;
    float* partial = ws + P_OFF;
    float* wT      = ws + WT_OFF;
    float* asqp    = ws + ASQ_OFF;
    float* afT     = ws + AFT_OFF;

    kW<<<CC / 256, 256, 0, stream>>>(w_land, wT, asqp);
    kA<<<dim3(BB, CSPLIT), 256, 0, stream>>>(feat, wT, partial);
    kB<<<BB * 4, 256, 0, stream>>>(partial, asqp, maps, dist);
    kC<<<dim3(CC / KCH, BB), 256, 0, stream>>>(feat, maps, modulation, af, afT);
    kD<<<BB * NCLS / 2 / 4, 256, 0, stream>>>(afT, w_cls, scores);
}